// Round 6
// baseline (116.058 us; speedup 1.0000x reference)
//
#include <hip/hip_runtime.h>

#define BB 4
#define NN 1024
#define EE 32
#define BLOCK 256
#define TI 4                 // i-rows per block
#define CHUNK 256            // j-rows staged per LDS chunk
#define NCHUNK (NN / CHUNK)  // 4

__global__ __launch_bounds__(BLOCK, 2) void anchor_loss_kernel(
    const float* __restrict__ emb,     // [B,N,E]
    const float* __restrict__ coords,  // [B,N,2]
    const int*   __restrict__ mask,    // [B,N,N] bool -> int32
    float* __restrict__ out)
{
    const int bid = blockIdx.x;        // B * (N/TI) = 1024 blocks
    const int b   = bid >> 8;
    const int it  = bid & 255;
    const int i0  = it * TI;
    const int tid = threadIdx.x;

    __shared__ float yj_s[CHUNK * EE];            // 32 KB, XOR-swizzled quads
    __shared__ float ex_s[NCHUNK * TI][BLOCK];    // 16 KB: per-pair exp values
    __shared__ float yi_s[TI][EE];
    __shared__ float ni_s[TI];
    __shared__ float wred[4][TI];
    __shared__ float wred2[4];

    const float* embb = emb    + (size_t)b * NN * EE;
    const float* crdb = coords + (size_t)b * NN * 2;

    // stage y_i rows (emb + coords folded into dims 0,1)
    if (tid < TI * EE) {
        const int r = tid >> 5, e = tid & 31;
        float v = embb[(i0 + r) * EE + e];
        if (e < 2) v += crdb[(i0 + r) * 2 + e];
        yi_s[r][e] = v;
    }
    __syncthreads();
    if (tid < TI) {
        float s = 0.f;
        #pragma unroll
        for (int e = 0; e < EE; ++e) { const float v = yi_s[tid][e]; s += v * v; }
        ni_s[tid] = s;
    }

    float    sum_part[TI];
    unsigned mbits = 0u;
    #pragma unroll
    for (int i = 0; i < TI; ++i) sum_part[i] = 0.f;

    #pragma unroll
    for (int c = 0; c < NCHUNK; ++c) {
        __syncthreads();   // yj_s reuse guard (also publishes yi_s/ni_s on c==0)

        // coalesced global -> LDS staging of 256 y_j rows, XOR-swizzled
        const float4* src4 = (const float4*)embb + (size_t)c * CHUNK * (EE / 4);
        #pragma unroll
        for (int w = 0; w < (CHUNK * EE / 4) / BLOCK; ++w) {   // 8 float4 / thread
            const int g = w * BLOCK + tid;                     // 0..2047
            const int r = g >> 3, q = g & 7;
            float4 v = src4[g];
            if (q == 0) {  // fold coords into dims 0,1
                v.x += crdb[(c * CHUNK + r) * 2 + 0];
                v.y += crdb[(c * CHUNK + r) * 2 + 1];
            }
            ((float4*)yj_s)[r * 8 + (q ^ (r & 7))] = v;
        }
        __syncthreads();

        // fused dot sweep: own y_j row streamed once (transient v),
        // 4 dot accumulators against broadcast yi reads -> tiny reg pressure
        float dot[TI] = {0.f, 0.f, 0.f, 0.f};
        float nj = 0.f;
        #pragma unroll
        for (int q = 0; q < 8; ++q) {
            const float4 v = ((const float4*)yj_s)[tid * 8 + (q ^ (tid & 7))];
            nj += v.x * v.x + v.y * v.y + v.z * v.z + v.w * v.w;
            #pragma unroll
            for (int i = 0; i < TI; ++i) {
                const float4 u = ((const float4*)yi_s[i])[q];   // broadcast
                dot[i] += u.x * v.x + u.y * v.y + u.z * v.z + u.w * v.w;
            }
        }

        const int j = c * CHUNK + tid;
        #pragma unroll
        for (int i = 0; i < TI; ++i) {
            float ssq = ni_s[i] + nj - 2.f * dot[i];
            ssq = fmaxf(ssq, 0.f);                         // cancellation/diag guard
            const float dist = sqrtf(ssq);
            const float sim  = 1.f / (1.f + __expf(dist - 5.f));
            const int   m    = mask[(size_t)(b * NN + i0 + i) * NN + j];
            const bool  negm = (m != 0) || (j == i0 + i);
            // single exp per pair: +sim for negatives, -sim for masked positives
            const float e    = __expf(m != 0 ? -sim : sim);
            sum_part[i] += negm ? 0.f : e;
            ex_s[c * TI + i][tid] = e;   // LDS, bank=tid%32 -> 2-way, free
            if (m != 0) mbits |= 1u << (c * TI + i);
        }
    }

    // block-reduce sum_part[i] over 256 threads -> total[i]
    #pragma unroll
    for (int i = 0; i < TI; ++i) {
        float s = sum_part[i];
        #pragma unroll
        for (int off = 32; off > 0; off >>= 1) s += __shfl_down(s, off, 64);
        if ((tid & 63) == 0) wred[tid >> 6][i] = s;
    }
    __syncthreads();
    float total[TI];
    #pragma unroll
    for (int i = 0; i < TI; ++i)
        total[i] = wred[0][i] + wred[1][i] + wred[2][i] + wred[3][i];
    // loss term per masked pair: logaddexp(sim,lse)-sim = log1p(total*exp(-sim))
    // all-masked row: total=0 -> log1p(0)=0  (correct)

    float acc = 0.f;
    #pragma unroll
    for (int c = 0; c < NCHUNK; ++c)
        #pragma unroll
        for (int i = 0; i < TI; ++i)
            if ((mbits >> (c * TI + i)) & 1u)
                acc += log1pf(total[i] * ex_s[c * TI + i][tid]);

    #pragma unroll
    for (int off = 32; off > 0; off >>= 1) acc += __shfl_down(acc, off, 64);
    if ((tid & 63) == 0) wred2[tid >> 6] = acc;
    __syncthreads();
    if (tid == 0) atomicAdd(out, wred2[0] + wred2[1] + wred2[2] + wred2[3]);
}

extern "C" void kernel_launch(void* const* d_in, const int* in_sizes, int n_in,
                              void* d_out, int out_size, void* d_ws, size_t ws_size,
                              hipStream_t stream) {
    const float* emb    = (const float*)d_in[0];
    const float* coords = (const float*)d_in[1];
    const int*   mask   = (const int*)d_in[2];
    float*       out    = (float*)d_out;

    hipMemsetAsync(out, 0, sizeof(float), stream);  // d_out is 0xAA-poisoned
    anchor_loss_kernel<<<BB * (NN / TI), BLOCK, 0, stream>>>(emb, coords, mask, out);
}

// Round 7
// 86.882 us; speedup vs baseline: 1.3358x; 1.3358x over previous
//
#include <hip/hip_runtime.h>

#define BBATCH 4
#define NN 1024
#define EE 32
#define NROW (BBATCH * NN)        // 4096

typedef short v8s __attribute__((ext_vector_type(8)));
typedef float v4f __attribute__((ext_vector_type(4)));

// ws layout (bytes):
//   yh   : bf16[NROW*EE]   @ 0         (262144)
//   nrm  : f32[NROW]       @ 262144
//   sums : f32[NROW]       @ 278528    (zeroed each call)
//   part : f32[1024]       @ 294912    (fully overwritten by passB)
#define WS_NRM  (NROW * EE * 2)
#define WS_SUM  (WS_NRM + NROW * 4)
#define WS_PART (WS_SUM + NROW * 4)

__device__ __forceinline__ unsigned short f32_to_bf16(float v) {
    unsigned u = __builtin_bit_cast(unsigned, v);
    u += 0x7fffu + ((u >> 16) & 1u);      // round-to-nearest-even
    return (unsigned short)(u >> 16);
}

// K1: y = emb (+coords on dims 0,1) -> bf16 yh + fp32 row norms
__global__ __launch_bounds__(256) void prep_kernel(
    const float* __restrict__ emb, const float* __restrict__ coords,
    unsigned short* __restrict__ yh, float* __restrict__ nrm)
{
    const int idx = blockIdx.x * 256 + threadIdx.x;   // 0 .. NROW*EE-1
    const int g = idx >> 5, e = idx & 31;
    float v = emb[idx];
    if (e < 2) v += coords[g * 2 + e];
    yh[idx] = f32_to_bf16(v);
    float s = v * v;                                   // row = 32 consecutive lanes
    #pragma unroll
    for (int off = 16; off > 0; off >>= 1) s += __shfl_xor(s, off, 32);
    if (e == 0) nrm[g] = s;
}

// K2: per row i, total_i = sum over non-(mask|diag) j of exp(sim_ij)
__global__ __launch_bounds__(256) void passA_kernel(
    const unsigned short* __restrict__ yh, const float* __restrict__ nrm,
    const int* __restrict__ mask, float* __restrict__ sums)
{
    const int bid = blockIdx.x;           // b(2) | istrip(6) | jg(2)
    const int jg = bid & 3;
    const int is = (bid >> 2) & 63;
    const int b  = bid >> 8;
    const int tid  = threadIdx.x;
    const int wave = tid >> 6, lane = tid & 63;
    const int m = lane & 15, q = lane >> 4;

    const int i0 = is * 16;
    const int rb = b * NN;                // batch row base
    // A fragment: A[m=lane&15][k=q*8+0..7] -> 16 B coalesced per lane
    const v8s af = *(const v8s*)(yh + (size_t)(rb + i0 + m) * EE + q * 8);
    float ni[4];
    #pragma unroll
    for (int r = 0; r < 4; ++r) ni[r] = nrm[rb + i0 + q * 4 + r];

    const int jbase = jg * 256 + wave * 64;
    float s[4] = {0.f, 0.f, 0.f, 0.f};

    #pragma unroll
    for (int t = 0; t < 4; ++t) {
        const int j0 = jbase + t * 16;
        const v8s bf = *(const v8s*)(yh + (size_t)(rb + j0 + m) * EE + q * 8);
        const float njv = nrm[rb + j0 + m];           // column j = j0+m
        int mk[4];
        #pragma unroll
        for (int r = 0; r < 4; ++r)
            mk[r] = mask[((size_t)(rb + i0 + q * 4 + r) << 10) + j0 + m];
        v4f d = __builtin_amdgcn_mfma_f32_16x16x32_bf16(af, bf, (v4f){0,0,0,0}, 0, 0, 0);
        #pragma unroll
        for (int r = 0; r < 4; ++r) {                 // D row = q*4+r, col = m
            float ssq  = fmaxf(ni[r] + njv - 2.f * d[r], 0.f);
            float dist = sqrtf(ssq);
            float sim  = 1.f / (1.f + __expf(dist - 5.f));
            bool negm  = (mk[r] != 0) || (i0 + q * 4 + r == j0 + m);
            s[r] += negm ? 0.f : __expf(sim);
        }
    }
    // reduce each row-sum across the 16 lanes of the quad, one atomic per row
    #pragma unroll
    for (int r = 0; r < 4; ++r) {
        float v = s[r];
        #pragma unroll
        for (int off = 8; off > 0; off >>= 1) v += __shfl_down(v, off, 16);
        if (m == 0) atomicAdd(&sums[rb + i0 + q * 4 + r], v);
    }
}

// K3: loss partials: sum over masked (i,j) of log1p(total_i * exp(-sim_ij))
__global__ __launch_bounds__(256) void passB_kernel(
    const unsigned short* __restrict__ yh, const float* __restrict__ nrm,
    const int* __restrict__ mask, const float* __restrict__ sums,
    float* __restrict__ part)
{
    const int bid = blockIdx.x;
    const int jg = bid & 3;
    const int is = (bid >> 2) & 63;
    const int b  = bid >> 8;
    const int tid  = threadIdx.x;
    const int wave = tid >> 6, lane = tid & 63;
    const int m = lane & 15, q = lane >> 4;

    const int i0 = is * 16;
    const int rb = b * NN;
    const v8s af = *(const v8s*)(yh + (size_t)(rb + i0 + m) * EE + q * 8);
    float ni[4], tot[4];
    #pragma unroll
    for (int r = 0; r < 4; ++r) {
        ni[r]  = nrm[rb + i0 + q * 4 + r];
        tot[r] = sums[rb + i0 + q * 4 + r];
    }

    const int jbase = jg * 256 + wave * 64;
    float acc = 0.f;

    #pragma unroll
    for (int t = 0; t < 4; ++t) {
        const int j0 = jbase + t * 16;
        const v8s bf = *(const v8s*)(yh + (size_t)(rb + j0 + m) * EE + q * 8);
        const float njv = nrm[rb + j0 + m];
        int mk[4];
        #pragma unroll
        for (int r = 0; r < 4; ++r)
            mk[r] = mask[((size_t)(rb + i0 + q * 4 + r) << 10) + j0 + m];
        v4f d = __builtin_amdgcn_mfma_f32_16x16x32_bf16(af, bf, (v4f){0,0,0,0}, 0, 0, 0);
        #pragma unroll
        for (int r = 0; r < 4; ++r) {
            float ssq  = fmaxf(ni[r] + njv - 2.f * d[r], 0.f);
            float dist = sqrtf(ssq);
            float sim  = 1.f / (1.f + __expf(dist - 5.f));
            // logaddexp(sim, lse) - sim = log(1 + total*exp(-sim)); total=0 -> 0
            float term = __logf(fmaf(tot[r], __expf(-sim), 1.f));
            acc += (mk[r] != 0) ? term : 0.f;
        }
    }

    __shared__ float wred[4];
    #pragma unroll
    for (int off = 32; off > 0; off >>= 1) acc += __shfl_down(acc, off, 64);
    if (lane == 0) wred[wave] = acc;
    __syncthreads();
    if (tid == 0) part[bid] = wred[0] + wred[1] + wred[2] + wred[3];
}

// K4: 1024 partials -> out[0]
__global__ __launch_bounds__(256) void reduce_kernel(
    const float* __restrict__ part, float* __restrict__ out)
{
    const int tid = threadIdx.x;
    float s = part[tid] + part[tid + 256] + part[tid + 512] + part[tid + 768];
    #pragma unroll
    for (int off = 32; off > 0; off >>= 1) s += __shfl_down(s, off, 64);
    __shared__ float w[4];
    if ((tid & 63) == 0) w[tid >> 6] = s;
    __syncthreads();
    if (tid == 0) out[0] = w[0] + w[1] + w[2] + w[3];
}

extern "C" void kernel_launch(void* const* d_in, const int* in_sizes, int n_in,
                              void* d_out, int out_size, void* d_ws, size_t ws_size,
                              hipStream_t stream) {
    const float* emb    = (const float*)d_in[0];
    const float* coords = (const float*)d_in[1];
    const int*   mask   = (const int*)d_in[2];

    char* ws = (char*)d_ws;
    unsigned short* yh   = (unsigned short*)ws;
    float*          nrm  = (float*)(ws + WS_NRM);
    float*          sums = (float*)(ws + WS_SUM);
    float*          part = (float*)(ws + WS_PART);

    hipMemsetAsync(sums, 0, NROW * sizeof(float), stream);  // ws is 0xAA-poisoned
    prep_kernel  <<<(NROW * EE) / 256, 256, 0, stream>>>(emb, coords, yh, nrm);
    passA_kernel <<<1024, 256, 0, stream>>>(yh, nrm, mask, sums);
    passB_kernel <<<1024, 256, 0, stream>>>(yh, nrm, mask, sums, part);
    reduce_kernel<<<1, 256, 0, stream>>>(part, (float*)d_out);
}

// Round 8
// 80.936 us; speedup vs baseline: 1.4339x; 1.0735x over previous
//
#include <hip/hip_runtime.h>

#define BBATCH 4
#define NN 1024
#define EE 32
#define NROW (BBATCH * NN)        // 4096

typedef short v8s __attribute__((ext_vector_type(8)));
typedef float v4f __attribute__((ext_vector_type(4)));

// ws layout: yh bf16[NROW*EE] @0 ; nrm f32[NROW] @WS_NRM
#define WS_NRM  (NROW * EE * 2)

__device__ __forceinline__ unsigned short f32_to_bf16(float v) {
    unsigned u = __builtin_bit_cast(unsigned, v);
    u += 0x7fffu + ((u >> 16) & 1u);      // round-to-nearest-even
    return (unsigned short)(u >> 16);
}

// K1: y = emb (+coords on dims 0,1) -> bf16 yh + fp32 row norms
__global__ __launch_bounds__(256) void prep_kernel(
    const float* __restrict__ emb, const float* __restrict__ coords,
    unsigned short* __restrict__ yh, float* __restrict__ nrm)
{
    const int idx = blockIdx.x * 256 + threadIdx.x;   // 0 .. NROW*EE-1
    const int g = idx >> 5, e = idx & 31;
    float v = emb[idx];
    if (e < 2) v += coords[g * 2 + e];
    yh[idx] = f32_to_bf16(v);
    float s = v * v;                                   // row = 32 consecutive lanes
    #pragma unroll
    for (int off = 16; off > 0; off >>= 1) s += __shfl_xor(s, off, 32);
    if (e == 0) nrm[g] = s;
}

// K2 (fused): block = 16-row strip x all 1024 j.  Phase 1 computes sim for all
// pairs (MFMA Gram tiles) + per-row sum of exp(sim) over negatives (block-local
// LDS reduction).  Phase 2 reuses register-held sim for the masked-pair loss.
__global__ __launch_bounds__(1024) void fused_kernel(
    const unsigned short* __restrict__ yh, const float* __restrict__ nrm,
    const int* __restrict__ mask, float* __restrict__ out)
{
    const int bid = blockIdx.x;           // b(2) | istrip(6)
    const int is = bid & 63;
    const int b  = bid >> 6;
    const int tid  = threadIdx.x;
    const int wave = tid >> 6, lane = tid & 63;
    const int m = lane & 15, q = lane >> 4;

    const int i0 = is * 16;
    const int rb = b * NN;
    // A fragment: A[m=lane&15][k=q*8+0..7] -> 16 B coalesced per lane
    const v8s af = *(const v8s*)(yh + (size_t)(rb + i0 + m) * EE + q * 8);
    float ni[4];
    #pragma unroll
    for (int r = 0; r < 4; ++r) ni[r] = nrm[rb + i0 + q * 4 + r];

    const int jbase = wave * 64;          // 16 waves cover j = 0..1023
    float    sim[4][4];
    float    s[4] = {0.f, 0.f, 0.f, 0.f};
    unsigned mbits = 0u;

    #pragma unroll
    for (int t = 0; t < 4; ++t) {
        const int j0 = jbase + t * 16;
        const v8s bf = *(const v8s*)(yh + (size_t)(rb + j0 + m) * EE + q * 8);
        const float njv = nrm[rb + j0 + m];           // column j = j0+m
        int mk[4];
        #pragma unroll
        for (int r = 0; r < 4; ++r)
            mk[r] = mask[((size_t)(rb + i0 + q * 4 + r) << 10) + j0 + m];
        v4f d = __builtin_amdgcn_mfma_f32_16x16x32_bf16(af, bf, (v4f){0,0,0,0}, 0, 0, 0);
        #pragma unroll
        for (int r = 0; r < 4; ++r) {                 // D row = q*4+r, col = m
            float ssq  = fmaxf(ni[r] + njv - 2.f * d[r], 0.f);
            float dist = sqrtf(ssq);
            float sm   = 1.f / (1.f + __expf(dist - 5.f));
            sim[t][r]  = sm;
            bool negm  = (mk[r] != 0) || (i0 + q * 4 + r == j0 + m);
            s[r] += negm ? 0.f : __expf(sm);
            if (mk[r] != 0) mbits |= 1u << (t * 4 + r);
        }
    }

    // per-row totals: quad-reduce (16 lanes) -> LDS[wave][row] -> sum 16 waves
    __shared__ float sums_w[16][16];
    __shared__ float total_s[16];
    __shared__ float wred[16];
    #pragma unroll
    for (int r = 0; r < 4; ++r) {
        float v = s[r];
        #pragma unroll
        for (int off = 8; off > 0; off >>= 1) v += __shfl_down(v, off, 16);
        if (m == 0) sums_w[wave][q * 4 + r] = v;
    }
    __syncthreads();
    if (tid < 16) {
        float tot = 0.f;
        #pragma unroll
        for (int w = 0; w < 16; ++w) tot += sums_w[w][tid];
        total_s[tid] = tot;
    }
    __syncthreads();

    // phase 2: masked pairs, term = log1p(total_i * exp(-sim))   (total=0 -> 0)
    float tot[4];
    #pragma unroll
    for (int r = 0; r < 4; ++r) tot[r] = total_s[q * 4 + r];
    float acc = 0.f;
    #pragma unroll
    for (int t = 0; t < 4; ++t)
        #pragma unroll
        for (int r = 0; r < 4; ++r)
            if ((mbits >> (t * 4 + r)) & 1u)
                acc += __logf(fmaf(tot[r], __expf(-sim[t][r]), 1.f));

    #pragma unroll
    for (int off = 32; off > 0; off >>= 1) acc += __shfl_down(acc, off, 64);
    if (lane == 0) wred[wave] = acc;
    __syncthreads();
    if (tid == 0) {
        float a = 0.f;
        #pragma unroll
        for (int w = 0; w < 16; ++w) a += wred[w];
        atomicAdd(out, a);                // 256 atomics total
    }
}

extern "C" void kernel_launch(void* const* d_in, const int* in_sizes, int n_in,
                              void* d_out, int out_size, void* d_ws, size_t ws_size,
                              hipStream_t stream) {
    const float* emb    = (const float*)d_in[0];
    const float* coords = (const float*)d_in[1];
    const int*   mask   = (const int*)d_in[2];
    float*       out    = (float*)d_out;

    char* ws = (char*)d_ws;
    unsigned short* yh  = (unsigned short*)ws;
    float*          nrm = (float*)(ws + WS_NRM);

    hipMemsetAsync(out, 0, sizeof(float), stream);   // d_out is 0xAA-poisoned
    prep_kernel <<<(NROW * EE) / 256, 256, 0, stream>>>(emb, coords, yh, nrm);
    fused_kernel<<<BBATCH * (NN / 16), 1024, 0, stream>>>(yh, nrm, mask, out);
}

// Round 9
// 80.858 us; speedup vs baseline: 1.4353x; 1.0010x over previous
//
#include <hip/hip_runtime.h>

#define BBATCH 4
#define NN 1024
#define EE 32

typedef short v8s __attribute__((ext_vector_type(8)));
typedef float v4f __attribute__((ext_vector_type(4)));

__device__ __forceinline__ unsigned short f32_to_bf16(float v) {
    unsigned u = __builtin_bit_cast(unsigned, v);
    u += 0x7fffu + ((u >> 16) & 1u);      // round-to-nearest-even
    return (unsigned short)(u >> 16);
}

// One block = 16-row strip x all 1024 j of one batch.  Phase 0 stages the
// batch's Y (emb + coords folded, bf16) into LDS (XOR-quad swizzled) + fp32
// norms.  Phase 1: MFMA Gram tiles -> sim; per-row sum of exp(sim) over
// negatives (block-local).  Phase 2: masked-pair loss from register-held
// exp(-sim).  One atomicAdd per block.
__global__ __launch_bounds__(1024) void fused_kernel(
    const float* __restrict__ emb, const float* __restrict__ coords,
    const int* __restrict__ mask, float* __restrict__ out)
{
    const int bid = blockIdx.x;           // b(2) | istrip(6)
    const int is = bid & 63;
    const int b  = bid >> 6;
    const int tid  = threadIdx.x;
    const int wave = tid >> 6, lane = tid & 63;
    const int m = lane & 15, q = lane >> 4;

    __shared__ unsigned short yh_s[NN * EE];   // 64 KB bf16, swizzled quads
    __shared__ float nrm_s[NN];                // 4 KB
    __shared__ float sums_w[16][16];
    __shared__ float total_s[16];
    __shared__ float wred[16];

    // ---- phase 0: stage batch Y -> LDS (coalesced), norms via 8-lane reduce
    const float4* src4 = (const float4*)(emb + (size_t)b * NN * EE);
    const float*  crdb = coords + (size_t)b * NN * 2;
    #pragma unroll
    for (int w = 0; w < 8; ++w) {              // 8192 float4 total
        const int g  = w * 1024 + tid;
        const int r  = g >> 3, qq = g & 7;     // row, quad
        float4 v = src4[g];
        if (qq == 0) { v.x += crdb[r * 2 + 0]; v.y += crdb[r * 2 + 1]; }
        ushort4 h;
        h.x = f32_to_bf16(v.x); h.y = f32_to_bf16(v.y);
        h.z = f32_to_bf16(v.z); h.w = f32_to_bf16(v.w);
        ((ushort4*)yh_s)[r * 8 + (qq ^ (r & 7))] = h;   // XOR-quad swizzle
        float p = v.x * v.x + v.y * v.y + v.z * v.z + v.w * v.w;
        #pragma unroll
        for (int off = 1; off < 8; off <<= 1) p += __shfl_xor(p, off, 64);
        if (qq == 0) nrm_s[r] = p;             // fp32 norm of exact y
    }
    __syncthreads();

    // ---- phase 1: Gram tiles + negative-exp row sums
    const int i0 = is * 16;
    // A fragment: A[m][k=q*8+0..7]; swizzled quad -> conflict-free ds_read_b128
    const v8s af = *(const v8s*)(yh_s + ((i0 + m) * EE) + ((q ^ (m & 7)) * 8));
    float ni[4];
    #pragma unroll
    for (int r = 0; r < 4; ++r) ni[r] = nrm_s[i0 + q * 4 + r];

    const int jbase = wave * 64;               // 16 waves cover j = 0..1023
    float    ex[4][4];                         // exp(-sim) masked / exp(sim) neg
    float    s[4] = {0.f, 0.f, 0.f, 0.f};
    unsigned mbits = 0u;

    #pragma unroll
    for (int t = 0; t < 4; ++t) {
        const int j0 = jbase + t * 16;
        const v8s bf = *(const v8s*)(yh_s + ((j0 + m) * EE) + ((q ^ (m & 7)) * 8));
        const float njv = nrm_s[j0 + m];       // column j = j0+m
        int mk[4];
        #pragma unroll
        for (int r = 0; r < 4; ++r)
            mk[r] = mask[((size_t)(b * NN + i0 + q * 4 + r) << 10) + j0 + m];
        v4f d = __builtin_amdgcn_mfma_f32_16x16x32_bf16(af, bf, (v4f){0,0,0,0}, 0, 0, 0);
        #pragma unroll
        for (int r = 0; r < 4; ++r) {          // D row = q*4+r, col = m
            float ssq  = fmaxf(ni[r] + njv - 2.f * d[r], 0.f);
            float dist = sqrtf(ssq);
            float sm   = 1.f / (1.f + __expf(dist - 5.f));
            // single exp: -sim for masked (pass 2), +sim for negatives (sum)
            const float e = __expf(mk[r] != 0 ? -sm : sm);
            ex[t][r] = e;
            bool negm = (mk[r] != 0) || (i0 + q * 4 + r == j0 + m);
            s[r] += negm ? 0.f : e;
            if (mk[r] != 0) mbits |= 1u << (t * 4 + r);
        }
    }

    // per-row totals: quad-reduce (16 lanes) -> LDS[wave][row] -> sum 16 waves
    #pragma unroll
    for (int r = 0; r < 4; ++r) {
        float v = s[r];
        #pragma unroll
        for (int off = 8; off > 0; off >>= 1) v += __shfl_down(v, off, 16);
        if (m == 0) sums_w[wave][q * 4 + r] = v;
    }
    __syncthreads();
    if (tid < 16) {
        float tot = 0.f;
        #pragma unroll
        for (int w = 0; w < 16; ++w) tot += sums_w[w][tid];
        total_s[tid] = tot;
    }
    __syncthreads();

    // ---- phase 2: masked pairs, term = log1p(total_i * exp(-sim)); total=0 -> 0
    float tot[4];
    #pragma unroll
    for (int r = 0; r < 4; ++r) tot[r] = total_s[q * 4 + r];
    float acc = 0.f;
    #pragma unroll
    for (int t = 0; t < 4; ++t)
        #pragma unroll
        for (int r = 0; r < 4; ++r)
            if ((mbits >> (t * 4 + r)) & 1u)
                acc += __logf(fmaf(tot[r], ex[t][r], 1.f));

    #pragma unroll
    for (int off = 32; off > 0; off >>= 1) acc += __shfl_down(acc, off, 64);
    if (lane == 0) wred[wave] = acc;
    __syncthreads();
    if (tid == 0) {
        float a = 0.f;
        #pragma unroll
        for (int w = 0; w < 16; ++w) a += wred[w];
        atomicAdd(out, a);                     // 256 atomics total
    }
}

extern "C" void kernel_launch(void* const* d_in, const int* in_sizes, int n_in,
                              void* d_out, int out_size, void* d_ws, size_t ws_size,
                              hipStream_t stream) {
    const float* emb    = (const float*)d_in[0];
    const float* coords = (const float*)d_in[1];
    const int*   mask   = (const int*)d_in[2];
    float*       out    = (float*)d_out;

    hipMemsetAsync(out, 0, sizeof(float), stream);   // d_out is 0xAA-poisoned
    fused_kernel<<<BBATCH * (NN / 16), 1024, 0, stream>>>(emb, coords, mask, out);
}